// Round 1
// baseline (1269.506 us; speedup 1.0000x reference)
//
#include <hip/hip_runtime.h>
#include <hip/hip_bf16.h>

// ---------------------------------------------------------------------------
// WindowAttention (Swin-style), MI355X / gfx950
//   x:(2048,49,512) f32  -> qkv GEMM (bf16 MFMA) -> per-(b,h) attention (VALU)
//   -> proj GEMM (bf16 MFMA) -> out f32
// ---------------------------------------------------------------------------

typedef __bf16  bf16x8 __attribute__((ext_vector_type(8)));
typedef float   f32x4  __attribute__((ext_vector_type(4)));

#define B_TOT   2048
#define NTOK    49
#define CDIM    512
#define NHEAD   16
#define HDIM    32
#define MROWS   (B_TOT * NTOK)      // 100352
#define QKVN    (3 * CDIM)          // 1536

// ---- async global->LDS, 16B per lane --------------------------------------
__device__ __forceinline__ void load_lds16(const void* gptr, void* lptr) {
    __builtin_amdgcn_global_load_lds(
        (const __attribute__((address_space(1))) unsigned int*)gptr,
        (__attribute__((address_space(3))) unsigned int*)lptr,
        16, 0, 0);
}

// ---- fp32 -> bf16 convert (vectorized, n multiple of 4) --------------------
__global__ void cvt_f32_bf16(const float* __restrict__ in,
                             __hip_bfloat16* __restrict__ out, int n4) {
    int idx = blockIdx.x * blockDim.x + threadIdx.x;
    int stride = gridDim.x * blockDim.x;
    for (int i = idx; i < n4; i += stride) {
        float4 f = ((const float4*)in)[i];
        union { __hip_bfloat16 h[4]; ushort4 u; } c;
        c.h[0] = __float2bfloat16(f.x);
        c.h[1] = __float2bfloat16(f.y);
        c.h[2] = __float2bfloat16(f.z);
        c.h[3] = __float2bfloat16(f.w);
        ((ushort4*)out)[i] = c.u;
    }
}

// ---- C = A @ B^T + bias : A (M,K) bf16 rm, B (N,K) bf16 rm -----------------
// 128x128 tile, BK=32, 4 waves (2x2 of 64x64), 16x16x32 bf16 MFMA.
// M%128==0, N%128==0, K%32==0 (all true here) -> no bounds checks.
template <typename OutT>
__global__ __launch_bounds__(256) void gemm_bt(
    const __hip_bfloat16* __restrict__ A,
    const __hip_bfloat16* __restrict__ B,
    const float* __restrict__ bias,
    OutT* __restrict__ C,
    int M, int N, int K)
{
    __shared__ __align__(16) __hip_bfloat16 As[128 * 32];
    __shared__ __align__(16) __hip_bfloat16 Bs[128 * 32];

    const int tid  = threadIdx.x;
    const int lane = tid & 63;
    const int wave = tid >> 6;
    const int wm   = (wave >> 1) * 64;
    const int wn   = (wave & 1) * 64;
    const int quad = lane >> 4;
    const int l16  = lane & 15;

    const int m0 = blockIdx.y * 128;
    const int n0 = blockIdx.x * 128;

    // staging: 2 chunks of 8 bf16 (16B) per thread per matrix
    const int off0 = tid * 8;             // elems
    const int off1 = (256 + tid) * 8;
    const int r0 = off0 >> 5, c0 = off0 & 31;
    const int r1 = off1 >> 5, c1 = off1 & 31;

    const __hip_bfloat16* Ab = A + (long)m0 * K;
    const __hip_bfloat16* Bb = B + (long)n0 * K;

    f32x4 acc[4][4] = {};

    for (int k0 = 0; k0 < K; k0 += 32) {
        load_lds16(Ab + (long)r0 * K + k0 + c0, &As[off0]);
        load_lds16(Ab + (long)r1 * K + k0 + c1, &As[off1]);
        load_lds16(Bb + (long)r0 * K + k0 + c0, &Bs[off0]);
        load_lds16(Bb + (long)r1 * K + k0 + c1, &Bs[off1]);
        __syncthreads();

        bf16x8 a[4], b[4];
#pragma unroll
        for (int i = 0; i < 4; ++i)
            a[i] = *(const bf16x8*)&As[(wm + i * 16 + l16) * 32 + quad * 8];
#pragma unroll
        for (int j = 0; j < 4; ++j)
            b[j] = *(const bf16x8*)&Bs[(wn + j * 16 + l16) * 32 + quad * 8];
#pragma unroll
        for (int i = 0; i < 4; ++i)
#pragma unroll
            for (int j = 0; j < 4; ++j)
                acc[i][j] = __builtin_amdgcn_mfma_f32_16x16x32_bf16(
                    a[i], b[j], acc[i][j], 0, 0, 0);
        __syncthreads();
    }

    // epilogue: D[row][col], col = lane&15, row = quad*4 + reg (verified m89/m91)
#pragma unroll
    for (int i = 0; i < 4; ++i) {
#pragma unroll
        for (int j = 0; j < 4; ++j) {
            const int col = n0 + wn + j * 16 + l16;
            const float bv = bias[col];
#pragma unroll
            for (int r = 0; r < 4; ++r) {
                const int row = m0 + wm + i * 16 + quad * 4 + r;
                const float val = acc[i][j][r] + bv;
                if constexpr (sizeof(OutT) == 2)
                    C[(long)row * N + col] = __float2bfloat16(val);
                else
                    C[(long)row * N + col] = val;
            }
        }
    }
}

// ---- windowed attention, one block per (b, h) ------------------------------
// qkv: (B*49, 1536) bf16 with cols [q(512) | k(512) | v(512)], head h at h*32.
// out: (B*49, 512) bf16, col = h*32 + d  (== transpose(0,2,1,3) flatten).
__global__ __launch_bounds__(256) void attn_win(
    const __hip_bfloat16* __restrict__ qkv,
    const float* __restrict__ mask,        // (64, 49, 49)
    const float* __restrict__ bias_table,  // (169, 16)
    __hip_bfloat16* __restrict__ out)
{
    const int b = blockIdx.x >> 4;
    const int h = blockIdx.x & 15;
    const int t = threadIdx.x;

    __shared__ float sQ[NTOK * 33];
    __shared__ float sK[NTOK * 33];
    __shared__ float sV[NTOK * 33];
    __shared__ float sS[NTOK * 50];
    __shared__ float sInv[NTOK];

    const float scale = 0.17677669529663687f;  // 1/sqrt(32)
    const long base = (long)b * NTOK * QKVN + h * HDIM;

    for (int e = t; e < NTOK * HDIM; e += 256) {
        const int tok = e >> 5, d = e & 31;
        const long g = base + (long)tok * QKVN + d;
        sQ[tok * 33 + d] = __bfloat162float(qkv[g]) * scale;
        sK[tok * 33 + d] = __bfloat162float(qkv[g + 512]);
        sV[tok * 33 + d] = __bfloat162float(qkv[g + 1024]);
    }
    __syncthreads();

    // S = Q K^T + rel-pos-bias + window mask
    const float* mrow = mask + (long)(b & 63) * (NTOK * NTOK);
    for (int e = t; e < NTOK * NTOK; e += 256) {
        const int i = e / 49, j = e - i * 49;
        float acc = 0.f;
#pragma unroll
        for (int d = 0; d < HDIM; ++d)
            acc += sQ[i * 33 + d] * sK[j * 33 + d];
        const int ri = i / 7, ci = i - ri * 7;
        const int rj = j / 7, cj = j - rj * 7;
        const int rel = (ri - rj + 6) * 13 + (ci - cj + 6);
        acc += bias_table[rel * NHEAD + h] + mrow[e];
        sS[i * 50 + j] = acc;
    }
    __syncthreads();

    // softmax rows (unnormalized exp in LDS, 1/sum aside)
    if (t < NTOK) {
        float m = -1e30f;
        for (int j = 0; j < NTOK; ++j) m = fmaxf(m, sS[t * 50 + j]);
        float s = 0.f;
        for (int j = 0; j < NTOK; ++j) {
            const float e = __expf(sS[t * 50 + j] - m);
            sS[t * 50 + j] = e;
            s += e;
        }
        sInv[t] = 1.0f / s;
    }
    __syncthreads();

    // out = softmax(S) @ V
    for (int e = t; e < NTOK * HDIM; e += 256) {
        const int i = e >> 5, d = e & 31;
        float acc = 0.f;
#pragma unroll
        for (int j = 0; j < NTOK; ++j)
            acc += sS[i * 50 + j] * sV[j * 33 + d];
        out[(long)(b * NTOK + i) * CDIM + h * HDIM + d] =
            __float2bfloat16(acc * sInv[i]);
    }
}

// ---------------------------------------------------------------------------
extern "C" void kernel_launch(void* const* d_in, const int* in_sizes, int n_in,
                              void* d_out, int out_size, void* d_ws, size_t ws_size,
                              hipStream_t stream) {
    const float* x          = (const float*)d_in[0];
    const float* mask       = (const float*)d_in[1];
    const float* qkv_w      = (const float*)d_in[2];
    const float* qkv_b      = (const float*)d_in[3];
    const float* proj_w     = (const float*)d_in[4];
    const float* proj_b     = (const float*)d_in[5];
    const float* bias_table = (const float*)d_in[6];

    char* ws = (char*)d_ws;
    // layout (16B aligned):
    //   [0)            x_bf16 / attn_out_bf16 (aliased): 100352*512*2 = 102,760,448
    //   [102,760,448)  qkv_w bf16: 1536*512*2 = 1,572,864
    //   [104,333,312)  proj_w bf16: 512*512*2 = 524,288
    //   [104,857,600)  qkv bf16: 100352*1536*2 = 308,281,344   (end ~394 MiB)
    __hip_bfloat16* xb   = (__hip_bfloat16*)(ws);
    __hip_bfloat16* qw   = (__hip_bfloat16*)(ws + 102760448);
    __hip_bfloat16* pw   = (__hip_bfloat16*)(ws + 104333312);
    __hip_bfloat16* qkvb = (__hip_bfloat16*)(ws + 104857600);
    __hip_bfloat16* ao   = xb;  // attn out reuses x_bf16 (GEMM1 done by then)

    cvt_f32_bf16<<<32768, 256, 0, stream>>>(x, xb, (MROWS * CDIM) / 4);
    cvt_f32_bf16<<<768,   256, 0, stream>>>(qkv_w, qw, (QKVN * CDIM) / 4);
    cvt_f32_bf16<<<256,   256, 0, stream>>>(proj_w, pw, (CDIM * CDIM) / 4);

    gemm_bt<__hip_bfloat16><<<dim3(QKVN / 128, MROWS / 128), 256, 0, stream>>>(
        xb, qw, qkv_b, qkvb, MROWS, QKVN, CDIM);

    attn_win<<<B_TOT * NHEAD, 256, 0, stream>>>(qkvb, mask, bias_table, ao);

    gemm_bt<float><<<dim3(CDIM / 128, MROWS / 128), 256, 0, stream>>>(
        ao, pw, proj_b, (float*)d_out, MROWS, CDIM, CDIM);
}